// Round 1
// baseline (183.008 us; speedup 1.0000x reference)
//
#include <hip/hip_runtime.h>

#define IMG_H 480
#define IMG_W 480
#define ATT_H 30
#define ATT_W 30
#define ATT_N (ATT_H * ATT_W)
#define PAD 48
#define NCH 3
#define NB 32
#define STRIPS 16           // 480 rows / 30 rows per strip
#define ROWS_PER_STRIP 30

// Kernel 1: per-strip mask bbox. Each block computes theta (0.5*max) itself
// (deterministic, identical across blocks) and writes its strip's raw bbox to
// a private slot — no global atomics, no init dependency on ws contents.
__global__ void __launch_bounds__(256) mask_kernel(const float* __restrict__ atten,
                                                   int* __restrict__ strip_box) {
    const int strip = blockIdx.x;
    const int b = blockIdx.y;
    const int tid = threadIdx.x;
    __shared__ float s_att[ATT_N];
    __shared__ float s_red[4];
    __shared__ int s_box[4];   // minr, maxr, minc, maxc

    const float* a = atten + (size_t)b * ATT_N;
    for (int i = tid; i < ATT_N; i += 256) s_att[i] = a[i];
    if (tid == 0) { s_box[0] = IMG_H; s_box[1] = -1; s_box[2] = IMG_W; s_box[3] = -1; }
    __syncthreads();

    // block max over the 900 attention values (order-independent => exact)
    float m = -1e30f;
    for (int i = tid; i < ATT_N; i += 256) m = fmaxf(m, s_att[i]);
    #pragma unroll
    for (int off = 32; off > 0; off >>= 1) m = fmaxf(m, __shfl_down(m, off, 64));
    if ((tid & 63) == 0) s_red[tid >> 6] = m;
    __syncthreads();
    const float theta = 0.5f * fmaxf(fmaxf(s_red[0], s_red[1]), fmaxf(s_red[2], s_red[3]));

    const int y_base = strip * ROWS_PER_STRIP;
    int minr = IMG_H, maxr = -1, minc = IMG_W, maxc = -1;
    for (int p = tid; p < ROWS_PER_STRIP * IMG_W; p += 256) {
        const int yy = p / IMG_W;
        const int y = y_base + yy;
        const int x = p - yy * IMG_W;
        // source coords: (i+0.5)*(30/480) - 0.5, clipped — scale is exactly 1/16
        float sy = (y + 0.5f) * 0.0625f - 0.5f;
        sy = fminf(fmaxf(sy, 0.0f), (float)(ATT_H - 1));
        const float fy0 = floorf(sy);
        const int r0 = (int)fy0;
        const int r1 = min(r0 + 1, ATT_H - 1);
        const float wr = sy - fy0;

        float sx = (x + 0.5f) * 0.0625f - 0.5f;
        sx = fminf(fmaxf(sx, 0.0f), (float)(ATT_W - 1));
        const float fx0 = floorf(sx);
        const int c0 = (int)fx0;
        const int c1 = min(c0 + 1, ATT_W - 1);
        const float wc = sx - fx0;

        // same op order as reference: row blend first, then column blend
        const float rb0 = s_att[r0 * ATT_W + c0] * (1.0f - wr) + s_att[r1 * ATT_W + c0] * wr;
        const float rb1 = s_att[r0 * ATT_W + c1] * (1.0f - wr) + s_att[r1 * ATT_W + c1] * wr;
        const float v = rb0 * (1.0f - wc) + rb1 * wc;
        if (v >= theta) {
            minr = min(minr, y); maxr = max(maxr, y);
            minc = min(minc, x); maxc = max(maxc, x);
        }
    }
    atomicMin(&s_box[0], minr); atomicMax(&s_box[1], maxr);
    atomicMin(&s_box[2], minc); atomicMax(&s_box[3], maxc);
    __syncthreads();
    if (tid == 0) {
        int* dst = strip_box + ((size_t)b * STRIPS + strip) * 4;
        dst[0] = s_box[0]; dst[1] = s_box[1]; dst[2] = s_box[2]; dst[3] = s_box[3];
    }
}

// Kernel 2: one block per (b, y) output row, ALL 3 channels per block.
//  - bbox reduce + row coords computed once (was 3x across per-channel blocks)
//  - stride-1 pixel mapping: x = tid (+256) => tap gather lane-stride = scaleW
//    <= 1 float => <=2-way LDS bank aliasing (free on CDNA4), vs. the previous
//    float4-per-thread mapping whose stride-4 gather was an 8-way conflict
//    (8.1M SQ_LDS_BANK_CONFLICT cycles).
//  - 11.52 KB LDS, tiny VGPR => 8 blocks/CU = full 32 waves/CU occupancy.
// Per-pixel arithmetic is expression-for-expression identical to the previous
// passing kernel => bit-identical output.
__global__ void __launch_bounds__(256) blend_kernel(const float* __restrict__ images,
                                                    const int* __restrict__ strip_box,
                                                    float* __restrict__ out) {
    const int y = blockIdx.x;
    const int b = blockIdx.y;
    const int tid = threadIdx.x;
    __shared__ __align__(16) float s_rows[NCH][2][IMG_W];   // 11520 B

    // reduce strip bboxes (uniform address => scalar loads, L2-hit)
    int minr = IMG_H, maxr = -1, minc = IMG_W, maxc = -1;
    const int* sb = strip_box + (size_t)b * STRIPS * 4;
    #pragma unroll
    for (int s = 0; s < STRIPS; ++s) {
        minr = min(minr, sb[s * 4 + 0]); maxr = max(maxr, sb[s * 4 + 1]);
        minc = min(minc, sb[s * 4 + 2]); maxc = max(maxc, sb[s * 4 + 3]);
    }
    const int h0 = max(minr - PAD, 0);
    const int h1 = min(maxr + PAD, IMG_H);
    const int w0 = max(minc - PAD, 0);
    const int w1 = min(maxc + PAD, IMG_W);
    const float cropH = (float)(h1 - h0);
    const float cropW = (float)(w1 - w0);

    // row coords for this output row (reference op order)
    float sy = (y + 0.5f) * (cropH / (float)IMG_H) - 0.5f;
    sy = fminf(fmaxf(sy, 0.0f), cropH - 1.0f);
    const float fy0 = floorf(sy);
    const float fy1 = fminf(fy0 + 1.0f, cropH - 1.0f);
    const float wr = sy - fy0;
    const int r0 = h0 + (int)fy0;
    const int r1 = h0 + (int)fy1;

    const float* imgb = images + (size_t)b * NCH * IMG_H * IMG_W;

    // stage source rows r0,r1 for all 3 channels: 6 rows x 120 float4 = 720
    for (int i = tid; i < 6 * (IMG_W / 4); i += 256) {
        const int rowid = i / (IMG_W / 4);       // 0..5
        const int q = i - rowid * (IMG_W / 4);   // 0..119
        const int ch = rowid >> 1;
        const int r = (rowid & 1) ? r1 : r0;
        ((float4*)&s_rows[ch][rowid & 1][0])[q] =
            ((const float4*)(imgb + ((size_t)ch * IMG_H + r) * IMG_W))[q];
    }
    __syncthreads();

    const float scaleW = cropW / (float)IMG_W;
    for (int x = tid; x < IMG_W; x += 256) {
        float sx = (x + 0.5f) * scaleW - 0.5f;
        sx = fminf(fmaxf(sx, 0.0f), cropW - 1.0f);
        const float fx0 = floorf(sx);
        const float fx1 = fminf(fx0 + 1.0f, cropW - 1.0f);
        const float wc = sx - fx0;
        const int c0 = w0 + (int)fx0;
        const int c1 = w0 + (int)fx1;

        #pragma unroll
        for (int ch = 0; ch < NCH; ++ch) {
            const float v00 = s_rows[ch][0][c0];
            const float v10 = s_rows[ch][1][c0];
            const float v01 = s_rows[ch][0][c1];
            const float v11 = s_rows[ch][1][c1];
            const float rb0 = v00 * (1.0f - wr) + v10 * wr;
            const float rb1 = v01 * (1.0f - wr) + v11 * wr;
            const float patch = rb0 * (1.0f - wc) + rb1 * wc;
            const size_t off = ((size_t)b * NCH + ch) * (IMG_H * IMG_W)
                             + (size_t)y * IMG_W + x;
            const float base = images[off];
            out[off] = base * 0.6f + patch * 0.4f;
        }
    }
}

extern "C" void kernel_launch(void* const* d_in, const int* in_sizes, int n_in,
                              void* d_out, int out_size, void* d_ws, size_t ws_size,
                              hipStream_t stream) {
    const float* images = (const float*)d_in[0];
    const float* atten  = (const float*)d_in[1];
    float* out = (float*)d_out;
    int* strip_box = (int*)d_ws;   // 32 * 16 * 4 ints

    dim3 mgrid(STRIPS, NB);
    mask_kernel<<<mgrid, 256, 0, stream>>>(atten, strip_box);

    dim3 bgrid(IMG_H, NB);
    blend_kernel<<<bgrid, 256, 0, stream>>>(images, strip_box, out);
}